// Round 8
// baseline (520.555 us; speedup 1.0000x reference)
//
#include <hip/hip_runtime.h>
#include <cstddef>

#define H 300
#define RS 304            // row stride (halfs) for row-major bf16 buffers
#define MAXNB 6
#define ASTR 312          // LDS A-tile stride (halfs); 624 B rows, 16B-divisible

typedef __attribute__((ext_vector_type(8)))  short bf16x8;
typedef __attribute__((ext_vector_type(16))) float f32x16;

__device__ __forceinline__ float bf2f(unsigned short u) {
    return __uint_as_float(((unsigned int)u) << 16);
}
__device__ __forceinline__ unsigned short f2bf(float f) {
    unsigned int u = __float_as_uint(f);
    u += 0x7FFFu + ((u >> 16) & 1u);
    return (unsigned short)(u >> 16);
}
__device__ __forceinline__ unsigned int sub2bf(unsigned int a, unsigned int b) {
    float d0 = bf2f((unsigned short)(a & 0xFFFFu)) - bf2f((unsigned short)(b & 0xFFFFu));
    float d1 = bf2f((unsigned short)(a >> 16))     - bf2f((unsigned short)(b >> 16));
    return (unsigned int)f2bf(d0) | ((unsigned int)f2bf(d1) << 16);
}
// relu on two packed bf16 (zero the negative halves) — bit-exact vs fp32 relu.
__device__ __forceinline__ unsigned int relu2(unsigned int w) {
    unsigned int r = w;
    if (w & 0x80000000u) r &= 0x0000FFFFu;
    if (w & 0x00008000u) r &= 0xFFFF0000u;
    return r;
}
__device__ __forceinline__ uint4 relu4(uint4 v) {
    v.x = relu2(v.x); v.y = relu2(v.y); v.z = relu2(v.z); v.w = relu2(v.w);
    return v;
}
__device__ __forceinline__ uint4 subpack4(uint4 a, uint4 b) {
    uint4 r;
    r.x = sub2bf(a.x, b.x); r.y = sub2bf(a.y, b.y);
    r.z = sub2bf(a.z, b.z); r.w = sub2bf(a.w, b.w);
    return r;
}

// ---------------------------------------------------------------------------
// Fragment layout: element (m,k) at buf[((m_blk*S + s)*64 + lane)*8 + j],
// m = m_blk*32 + (lane&31), k = s*16 + (lane>>5)*8 + j. Same for B with n.

// Coalesced fragment pack for dense fp32 (used for f_atoms only): one block per
// 64-row tile; stage rows coalesced into LDS (bf16), then write fragments 16B/lane.
template<int S>
__global__ void __launch_bounds__(256)
pack_a_f32_c(const float* __restrict__ src, unsigned short* __restrict__ dst,
             int M, int K)
{
    __shared__ unsigned short sm[64 * 152];
    const int m0 = blockIdx.x * 64;
    const int r = threadIdx.x >> 2;
    const int q = threadIdx.x & 3;
    int mv = m0 + r; if (mv >= M) mv = M - 1;
    const float* rowF = src + (size_t)mv * K;
#pragma unroll
    for (int i = 0; i < (S * 4 + 3) / 4; ++i) {
        int c = q + i * 4;                    // chunk of 4 halfs
        if (c * 4 < S * 16) {
            unsigned short h[4];
#pragma unroll
            for (int e = 0; e < 4; ++e) {
                int k = c * 4 + e;
                h[e] = (k < K) ? f2bf(rowF[k]) : (unsigned short)0;
            }
            uint2 o;
            o.x = (unsigned int)h[0] | ((unsigned int)h[1] << 16);
            o.y = (unsigned int)h[2] | ((unsigned int)h[3] << 16);
            *(uint2*)&sm[r * 152 + c * 4] = o;
        }
    }
    __syncthreads();
    for (int j = threadIdx.x; j < 2 * S * 64; j += 256) {
        int lane = j & 63;
        int t = j >> 6;
        int s = t % S;
        int mb2 = t / S;
        uint4 v = *(const uint4*)&sm[(mb2 * 32 + (lane & 31)) * 152 + s * 16 + (lane >> 5) * 8];
        int m_blk = blockIdx.x * 2 + mb2;
        *(uint4*)&dst[((size_t)(m_blk * S + s) * 64 + lane) * 8] = v;
    }
}

__global__ void __launch_bounds__(256)
pack_b(const float* __restrict__ src1, const float* __restrict__ src2,
       unsigned short* __restrict__ dst, int K1, int S1, int K2, int SB)
{
    int g = blockIdx.x * 256 + threadIdx.x;
    if (g >= 10 * SB * 64) return;
    int lane = g & 63;
    int t = g >> 6;
    int s = t % SB;
    int n_blk = t / SB;
    int n = n_blk * 32 + (lane & 31);
    unsigned int w[4];
#pragma unroll
    for (int p = 0; p < 4; ++p) {
        unsigned short h[2];
#pragma unroll
        for (int e = 0; e < 2; ++e) {
            int kf = s * 16 + (lane >> 5) * 8 + p * 2 + e;
            float v = 0.0f;
            if (n < H) {
                if (s < S1) {
                    if (kf < K1) v = src1[(size_t)kf * H + n];
                } else {
                    int k2 = kf - S1 * 16;
                    if (k2 < K2) v = src2[(size_t)k2 * H + n];
                }
            }
            h[e] = f2bf(v);
        }
        w[p] = (unsigned int)h[0] | ((unsigned int)h[1] << 16);
    }
    *(uint4*)&dst[(size_t)g * 8] = make_uint4(w[0], w[1], w[2], w[3]);
}

// ---------------------------------------------------------------------------
// amsg[a][:] = sum_j maybe_relu(msg[a2b[a][j]][:]). One thread per 8 halfs.
template<int RELU>
__global__ void __launch_bounds__(256)
aggregate_row(const unsigned short* __restrict__ msg, const int* __restrict__ a2b,
              unsigned short* __restrict__ amsg, int n_atoms)
{
    int gid = blockIdx.x * 256 + threadIdx.x;
    int total = n_atoms * 38;
    if (gid >= total) return;
    int atom = gid / 38;
    int g8 = gid - atom * 38;
    const int* nb = a2b + atom * MAXNB;
    float sum[8] = {};
#pragma unroll
    for (int j = 0; j < MAXNB; ++j) {
        int b = nb[j];
        uint4 v = *(const uint4*)&msg[(size_t)b * RS + g8 * 8];
        if (RELU) v = relu4(v);
        unsigned int ww[4] = {v.x, v.y, v.z, v.w};
#pragma unroll
        for (int p = 0; p < 4; ++p) {
            sum[p * 2]     += bf2f((unsigned short)(ww[p] & 0xFFFFu));
            sum[p * 2 + 1] += bf2f((unsigned short)(ww[p] >> 16));
        }
    }
    unsigned int ow[4];
#pragma unroll
    for (int p = 0; p < 4; ++p)
        ow[p] = (unsigned int)f2bf(sum[p * 2]) | ((unsigned int)f2bf(sum[p * 2 + 1]) << 16);
    *(uint4*)&amsg[(size_t)atom * RS + g8 * 8] = make_uint4(ow[0], ow[1], ow[2], ow[3]);
}

// ---------------------------------------------------------------------------
// Fused MFMA GEMM. Geometry = R3/R7 (best): 64-row tile, 640 thr / 10 waves,
// wave = 1 N-block x 2 row-halves, acc[2] = 32 AGPR, launch_bounds(640,8).
// R8 change: DIRECT-GLOBAL epilogue. R7 evidence: init (STOT=10, streaming A,
// 30MB FETCH) == mp (STOT=19, gathers, 98MB) == ~66us -> per-block time is the
// fixed phase chain, and the C-through-LDS epilogue is 2 of the 3 barriers +
// an LDS round-trip + bank conflicts. MFMA C-layout stores straight to global
// with 64B-segment coalescing (fixed reg r: lanes 0..31 = cols 0..31 of one
// row, 2B each). Epilogue math moved into registers, bit-identical (keeps the
// f2bf->bf2f roundtrip of acc that the LDS path had). After the K-loop there
// are ZERO barriers; waves retire independently -> earlier slot release.
// MODE 0 (init): A = dense fp32 Adense staged fp32->bf16 in LDS. out = raw A@B.
// MODE 1 (mp):   A = LDS-staged (amsg[b2a[m]] - maybe_relu(msg[b2revb[m]])).
//                out = relu(A@B + inp_add).
// MODE 2 (cat):  A = [A1 packed | LDS-staged amsg rows]. out = relu(A@B + bias).
template<int S1, int S2, int SBL, int MODE, int RELUMSG>
__global__ void __launch_bounds__(640, 8)
gemm_fused(const unsigned short* __restrict__ A1,
           const unsigned short* __restrict__ amsg,
           const unsigned short* __restrict__ msg,
           const int* __restrict__ b2a, const int* __restrict__ b2revb,
           const unsigned short* __restrict__ Bp,
           const float* __restrict__ bias,
           const unsigned short* __restrict__ inp_add,
           const float* __restrict__ Adense, int Kd,
           unsigned short* __restrict__ out, int M)
{
    __shared__ __align__(16) unsigned short smem[64 * ASTR]; // A-tile only

    const int lane  = threadIdx.x & 63;
    const int w     = threadIdx.x >> 6;          // 0..9: N-block index
    const int mrow  = lane & 31;
    const int quad  = lane >> 5;
    const int m0    = blockIdx.x * 64;

    // ---- Stage A-tile: 512 threads, 8 threads/row, chunk set (t&7)+8i.
    if (threadIdx.x < 512) {
        const int r = threadIdx.x >> 3;          // 0..63
        const int q = threadIdx.x & 7;
        int mm = m0 + r;
        int mv = (mm < M) ? mm : 0;
        if (MODE == 0) {
            if (mm >= M) mv = M - 1;
            const float* rowF = Adense + (size_t)mv * Kd;
#pragma unroll
            for (int i = 0; i < 5; ++i) {
                int c = q + i * 8;              // chunk of 4 halfs, c < 40
                if (c * 4 < S2 * 16) {
                    unsigned short h[4];
#pragma unroll
                    for (int e = 0; e < 4; ++e) {
                        int k = c * 4 + e;
                        h[e] = (k < Kd) ? f2bf(rowF[k]) : (unsigned short)0;
                    }
                    uint2 o;
                    o.x = (unsigned int)h[0] | ((unsigned int)h[1] << 16);
                    o.y = (unsigned int)h[2] | ((unsigned int)h[3] << 16);
                    *(uint2*)&smem[r * ASTR + c * 4] = o;
                }
            }
        } else {
            const unsigned short* rowA;
            const unsigned short* rowM = nullptr;
            if (MODE == 1) {
                rowA = amsg + (size_t)b2a[mv] * RS;
                rowM = msg  + (size_t)b2revb[mv] * RS;
            } else {
                rowA = amsg + (size_t)mv * RS;
            }
#pragma unroll
            for (int i = 0; i < 5; ++i) {
                int c = q + i * 8;              // chunk of 8 halfs, c < 38
                if (c < 38) {
                    uint4 o;
                    if (MODE == 1) {
                        uint4 va = *(const uint4*)(rowA + c * 8);
                        uint4 vm = *(const uint4*)(rowM + c * 8);
                        if (RELUMSG) vm = relu4(vm);
                        o = subpack4(va, vm);
                    } else {
                        o = *(const uint4*)(rowA + c * 8);
                    }
                    *(uint4*)&smem[r * ASTR + c * 8] = o;
                }
            }
        }
    }
    __syncthreads();

    f32x16 acc_lo, acc_hi;
#pragma unroll
    for (int i = 0; i < 16; ++i) { acc_lo[i] = 0.0f; acc_hi[i] = 0.0f; }

    // A1 fragment pointers per row-half (32-row m_blk granularity).
    const unsigned short* pa1_lo = (S1 > 0)
        ? (A1 + ((size_t)(blockIdx.x * 2 + 0) * S1 * 64 + lane) * 8) : nullptr;
    const unsigned short* pa1_hi = (S1 > 0)
        ? (A1 + ((size_t)(blockIdx.x * 2 + 1) * S1 * 64 + lane) * 8) : nullptr;
    const unsigned short* pb = Bp + ((size_t)w * SBL * 64 + lane) * 8;

    constexpr int STOT = S1 + S2;

    auto loadA = [&](int s, const unsigned short* pa1x, int half) -> bf16x8 {
        if (s < S1) return *(const bf16x8*)(pa1x + (size_t)s * 512);
        return *(const bf16x8*)&smem[((half << 5) + mrow) * ASTR + (s - S1) * 16 + quad * 8];
    };

    bf16x8 b0, b1;
    b0 = *(const bf16x8*)(pb);
    if (STOT > 1) b1 = *(const bf16x8*)(pb + 512);

#pragma unroll
    for (int s = 0; s < STOT; s += 2) {
        bf16x8 a_lo = loadA(s, pa1_lo, 0);
        bf16x8 a_hi = loadA(s, pa1_hi, 1);
        acc_lo = __builtin_amdgcn_mfma_f32_32x32x16_bf16(a_lo, b0, acc_lo, 0, 0, 0);
        acc_hi = __builtin_amdgcn_mfma_f32_32x32x16_bf16(a_hi, b0, acc_hi, 0, 0, 0);
        if (s + 2 < STOT) b0 = *(const bf16x8*)(pb + (size_t)(s + 2) * 512);
        if (s + 1 < STOT) {
            bf16x8 a_lo2 = loadA(s + 1, pa1_lo, 0);
            bf16x8 a_hi2 = loadA(s + 1, pa1_hi, 1);
            acc_lo = __builtin_amdgcn_mfma_f32_32x32x16_bf16(a_lo2, b1, acc_lo, 0, 0, 0);
            acc_hi = __builtin_amdgcn_mfma_f32_32x32x16_bf16(a_hi2, b1, acc_hi, 0, 0, 0);
            if (s + 3 < STOT) b1 = *(const bf16x8*)(pb + (size_t)(s + 3) * 512);
        }
    }

    // ---- Direct-global epilogue: no barriers, no LDS round-trip.
    // acc reg r of half h -> row = h*32 + (r&3) + 8*(r>>2) + 4*quad,
    // col = w*32 + mrow. Bit-identical math to the LDS path (f2bf->bf2f
    // roundtrip of acc preserved).
    {
        const int colg = w * 32 + mrow;
        if (colg < 304) {
            const float bv = (MODE == 2) ? ((colg < H) ? bias[colg] : 0.0f) : 0.0f;
#pragma unroll
            for (int half = 0; half < 2; ++half) {
#pragma unroll
                for (int r = 0; r < 16; ++r) {
                    int row = half * 32 + (r & 3) + 8 * (r >> 2) + 4 * quad;
                    int mm = m0 + row;
                    if (mm >= M) continue;
                    float av = (half == 0) ? acc_lo[r] : acc_hi[r];
                    unsigned short hraw = f2bf(av);
                    unsigned short ho;
                    if (MODE == 0) {
                        ho = hraw;
                    } else {
                        float v = bf2f(hraw);
                        if (MODE == 1) {
                            v += bf2f(inp_add[(size_t)mm * RS + colg]);
                        } else {
                            v += bv;
                        }
                        ho = f2bf(fmaxf(v, 0.0f));
                    }
                    out[(size_t)mm * RS + colg] = ho;
                }
            }
        }
    }
}

// ---------------------------------------------------------------------------
__global__ void __launch_bounds__(128)
segmean_kernel(const unsigned short* __restrict__ ah,
               const int* __restrict__ mol_id, int n_atoms,
               float* __restrict__ out)
{
    int m = blockIdx.x;
    int lo = 0, hi = n_atoms;
    while (lo < hi) { int mid = (lo + hi) >> 1; if (mol_id[mid] < m) lo = mid + 1; else hi = mid; }
    int start = lo;
    hi = n_atoms;
    while (lo < hi) { int mid = (lo + hi) >> 1; if (mol_id[mid] < m + 1) lo = mid + 1; else hi = mid; }
    int end = lo;

    int c = threadIdx.x;
    float a0 = 0.f, a1 = 0.f, a2 = 0.f;
    for (int a = start; a < end; ++a) {
        const unsigned short* row = ah + (size_t)a * RS;
        a0 += bf2f(row[c]);
        a1 += bf2f(row[c + 128]);
        if (c < H - 256) a2 += bf2f(row[c + 256]);
    }
    float inv = (end > start) ? 1.0f / (float)(end - start) : 0.0f;
    float* orow = out + (size_t)m * H;
    orow[c] = a0 * inv;
    orow[c + 128] = a1 * inv;
    if (c < H - 256) orow[c + 256] = a2 * inv;
}

// ---------------------------------------------------------------------------
extern "C" void kernel_launch(void* const* d_in, const int* in_sizes, int n_in,
                              void* d_out, int out_size, void* d_ws, size_t ws_size,
                              hipStream_t stream)
{
    const float* f_atoms = (const float*)d_in[0];
    const float* f_bonds = (const float*)d_in[1];
    const int*   a2b     = (const int*)d_in[2];
    const int*   b2a     = (const int*)d_in[3];
    const int*   b2revb  = (const int*)d_in[4];
    const int*   mol_id  = (const int*)d_in[5];
    const float* W_i     = (const float*)d_in[7];
    const float* W_h     = (const float*)d_in[8];
    const float* W_o     = (const float*)d_in[9];
    const float* b_o     = (const float*)d_in[10];

    const int n_atoms   = in_sizes[5];
    const int n_bonds   = in_sizes[3];
    const int atom_fdim = in_sizes[0] / n_atoms;   // 133
    const int bond_fdim = in_sizes[1] / n_bonds;   // 147
    const int n_mols    = out_size / H;            // 2000

    const int gAtoms  = (n_atoms + 63) / 64;       // 64-row blocks
    const int gBonds  = (n_bonds + 63) / 64;

    const size_t bondsRS = (size_t)n_bonds * RS;
    const size_t atomsRS = (size_t)n_atoms * RS;
    const size_t wihSz   = 10 * 30 * 512;
    const size_t woSz    = 10 * 29 * 512;
    const size_t wh19Sz  = 10 * 19 * 512;

    // Layout (halfs): inp | msgB | amsg | wih | wo | wh19 | ah
    // Overlays: iter-2 mp writes message2 in-place over inp (audited safe);
    //           fap overlays inp after final aggregate.
    unsigned short* inp  = (unsigned short*)d_ws;
    unsigned short* msgB = inp  + bondsRS;
    unsigned short* amsg = msgB + bondsRS;
    unsigned short* wih  = amsg + atomsRS;
    unsigned short* wo   = wih  + wihSz;
    unsigned short* wh19 = wo   + woSz;
    unsigned short* ah   = wh19 + wh19Sz;
    unsigned short* fap  = inp;          // fap (14.4 MB) fits in inp (60.8 MB)

    dim3 blk(256);
    dim3 gblk(640);
    const int aggBlocks = (n_atoms * 38 + 255) / 256;

    pack_b<<<(10 * 30 * 64 + 255) / 256, blk, 0, stream>>>(W_i, W_h, wih, bond_fdim, 10, H, 30);
    pack_b<<<(10 * 19 * 64 + 255) / 256, blk, 0, stream>>>(W_h, W_h, wh19, H, 19, 0, 19);
    pack_b<<<(10 * 29 * 64 + 255) / 256, blk, 0, stream>>>(W_o, W_o + (size_t)atom_fdim * H, wo,
                                                           atom_fdim, 9, H, 29);

    // init: inp = f_bonds @ W_i  (raw; f_bonds staged fp32->bf16 in-kernel)
    gemm_fused<0, 10, 30, 0, 0><<<gBonds, gblk, 0, stream>>>(
        nullptr, nullptr, nullptr, nullptr, nullptr, wih, nullptr, nullptr,
        f_bonds, bond_fdim, inp, n_bonds);

    // iter 1: message1 = relu(inp + (amsg[b2a] - relu(inp[b2revb])) @ W_h) -> msgB
    aggregate_row<1><<<aggBlocks, blk, 0, stream>>>(inp, a2b, amsg, n_atoms);
    gemm_fused<0, 19, 19, 1, 1><<<gBonds, gblk, 0, stream>>>(
        nullptr, amsg, inp, b2a, b2revb, wh19, nullptr, inp, nullptr, 0, msgB, n_bonds);

    // iter 2: message2 -> inp (in-place; inp only read by this kernel's epilogue)
    aggregate_row<0><<<aggBlocks, blk, 0, stream>>>(msgB, a2b, amsg, n_atoms);
    gemm_fused<0, 19, 19, 1, 0><<<gBonds, gblk, 0, stream>>>(
        nullptr, amsg, msgB, b2a, b2revb, wh19, nullptr, inp, nullptr, 0, inp, n_bonds);

    // final aggregation from message2
    aggregate_row<0><<<aggBlocks, blk, 0, stream>>>(inp, a2b, amsg, n_atoms);

    // f_atoms pack, coalesced (overlays inp region — dead after final aggregate)
    pack_a_f32_c<9><<<gAtoms, blk, 0, stream>>>(f_atoms, fap, n_atoms, atom_fdim);

    // cat GEMM: ah = relu([f_atoms | amsg] @ W_o + b_o)
    gemm_fused<9, 19, 29, 2, 0><<<gAtoms, gblk, 0, stream>>>(
        fap, amsg, nullptr, nullptr, nullptr, wo, b_o, nullptr, nullptr, 0, ah, n_atoms);

    segmean_kernel<<<n_mols, dim3(128), 0, stream>>>(ah, mol_id, n_atoms, (float*)d_out);
}

// Round 9
// 475.152 us; speedup vs baseline: 1.0956x; 1.0956x over previous
//
#include <hip/hip_runtime.h>
#include <cstddef>

#define H 300
#define RS 304            // row stride (halfs) for row-major bf16 buffers
#define MAXNB 6
#define ASTR 312          // LDS A-tile stride (halfs); 624 B rows, 16B-divisible

typedef __attribute__((ext_vector_type(8)))  short bf16x8;
typedef __attribute__((ext_vector_type(16))) float f32x16;

__device__ __forceinline__ float bf2f(unsigned short u) {
    return __uint_as_float(((unsigned int)u) << 16);
}
__device__ __forceinline__ unsigned short f2bf(float f) {
    unsigned int u = __float_as_uint(f);
    u += 0x7FFFu + ((u >> 16) & 1u);
    return (unsigned short)(u >> 16);
}
__device__ __forceinline__ unsigned int sub2bf(unsigned int a, unsigned int b) {
    float d0 = bf2f((unsigned short)(a & 0xFFFFu)) - bf2f((unsigned short)(b & 0xFFFFu));
    float d1 = bf2f((unsigned short)(a >> 16))     - bf2f((unsigned short)(b >> 16));
    return (unsigned int)f2bf(d0) | ((unsigned int)f2bf(d1) << 16);
}
// relu on two packed bf16 (zero the negative halves) — bit-exact vs fp32 relu.
__device__ __forceinline__ unsigned int relu2(unsigned int w) {
    unsigned int r = w;
    if (w & 0x80000000u) r &= 0x0000FFFFu;
    if (w & 0x00008000u) r &= 0xFFFF0000u;
    return r;
}
__device__ __forceinline__ uint4 relu4(uint4 v) {
    v.x = relu2(v.x); v.y = relu2(v.y); v.z = relu2(v.z); v.w = relu2(v.w);
    return v;
}
__device__ __forceinline__ uint4 subpack4(uint4 a, uint4 b) {
    uint4 r;
    r.x = sub2bf(a.x, b.x); r.y = sub2bf(a.y, b.y);
    r.z = sub2bf(a.z, b.z); r.w = sub2bf(a.w, b.w);
    return r;
}

// ---------------------------------------------------------------------------
// Fragment layout: element (m,k) at buf[((m_blk*S + s)*64 + lane)*8 + j],
// m = m_blk*32 + (lane&31), k = s*16 + (lane>>5)*8 + j. Same for B with n.

__global__ void __launch_bounds__(256)
pack_b(const float* __restrict__ src1, const float* __restrict__ src2,
       unsigned short* __restrict__ dst, int K1, int S1, int K2, int SB)
{
    int g = blockIdx.x * 256 + threadIdx.x;
    if (g >= 10 * SB * 64) return;
    int lane = g & 63;
    int t = g >> 6;
    int s = t % SB;
    int n_blk = t / SB;
    int n = n_blk * 32 + (lane & 31);
    unsigned int w[4];
#pragma unroll
    for (int p = 0; p < 4; ++p) {
        unsigned short h[2];
#pragma unroll
        for (int e = 0; e < 2; ++e) {
            int kf = s * 16 + (lane >> 5) * 8 + p * 2 + e;
            float v = 0.0f;
            if (n < H) {
                if (s < S1) {
                    if (kf < K1) v = src1[(size_t)kf * H + n];
                } else {
                    int k2 = kf - S1 * 16;
                    if (k2 < K2) v = src2[(size_t)k2 * H + n];
                }
            }
            h[e] = f2bf(v);
        }
        w[p] = (unsigned int)h[0] | ((unsigned int)h[1] << 16);
    }
    *(uint4*)&dst[(size_t)g * 8] = make_uint4(w[0], w[1], w[2], w[3]);
}

// ---------------------------------------------------------------------------
// amsg[a][:] = sum_j maybe_relu(msg[a2b[a][j]][:]). One thread per 8 halfs.
template<int RELU>
__global__ void __launch_bounds__(256)
aggregate_row(const unsigned short* __restrict__ msg, const int* __restrict__ a2b,
              unsigned short* __restrict__ amsg, int n_atoms)
{
    int gid = blockIdx.x * 256 + threadIdx.x;
    int total = n_atoms * 38;
    if (gid >= total) return;
    int atom = gid / 38;
    int g8 = gid - atom * 38;
    const int* nb = a2b + atom * MAXNB;
    float sum[8] = {};
#pragma unroll
    for (int j = 0; j < MAXNB; ++j) {
        int b = nb[j];
        uint4 v = *(const uint4*)&msg[(size_t)b * RS + g8 * 8];
        if (RELU) v = relu4(v);
        unsigned int ww[4] = {v.x, v.y, v.z, v.w};
#pragma unroll
        for (int p = 0; p < 4; ++p) {
            sum[p * 2]     += bf2f((unsigned short)(ww[p] & 0xFFFFu));
            sum[p * 2 + 1] += bf2f((unsigned short)(ww[p] >> 16));
        }
    }
    unsigned int ow[4];
#pragma unroll
    for (int p = 0; p < 4; ++p)
        ow[p] = (unsigned int)f2bf(sum[p * 2]) | ((unsigned int)f2bf(sum[p * 2 + 1]) << 16);
    *(uint4*)&amsg[(size_t)atom * RS + g8 * 8] = make_uint4(ow[0], ow[1], ow[2], ow[3]);
}

// ---------------------------------------------------------------------------
// Fused MFMA GEMM. Geometry = R3/R7 (best): 64-row tile, 640 thr / 10 waves,
// wave = 1 N-block x 2 row-halves, acc[2] = 32 AGPR, launch_bounds(640,8),
// LDS epilogue (R8's direct-global stores regressed: 2B scalar stores/loads
// tripled memory instructions in an MLP-starved pipe).
// R9 change: MODE 3 fuses the FINAL aggregate + f_atoms pack into the cat
// GEMM staging (1:1 rows -> no request duplication, unlike R6): A-tile =
// [f2bf(f_atoms row) | sum_j msg2[a2b[row][j]]] staged into a 448-half/row
// LDS tile; removes aggregate_row + pack_a_f32_c dispatches and the amsg/fap
// intermediate round-trips. Math bit-identical (same fp32 sum + f2bf).
// MODE 0 (init): A = dense fp32 Adense staged fp32->bf16 in LDS. out = raw A@B.
// MODE 1 (mp):   A = LDS-staged (amsg[b2a[m]] - maybe_relu(msg[b2revb[m]])).
//                out = relu(A@B + inp_add).
// MODE 3 (catf): A = [f_atoms | Sum msg[a2b]] all-LDS. out = relu(A@B + bias).
template<int S1, int S2, int SBL, int MODE, int RELUMSG>
__global__ void __launch_bounds__(640, 8)
gemm_fused(const unsigned short* __restrict__ A1,
           const unsigned short* __restrict__ amsg,
           const unsigned short* __restrict__ msg,
           const int* __restrict__ b2a, const int* __restrict__ b2revb,
           const unsigned short* __restrict__ Bp,
           const float* __restrict__ bias,
           const unsigned short* __restrict__ inp_add,
           const float* __restrict__ Adense, int Kd,
           unsigned short* __restrict__ out, int M)
{
    constexpr int STR = (MODE == 3) ? 456 : 312;   // LDS A row stride (halfs)
    __shared__ __align__(16) unsigned short smem[64 * STR]; // Ast / Cs union

    const int lane  = threadIdx.x & 63;
    const int w     = threadIdx.x >> 6;          // 0..9: N-block index
    const int mrow  = lane & 31;
    const int quad  = lane >> 5;
    const int m0    = blockIdx.x * 64;

    // ---- Stage A-tile: 512 threads, 8 threads/row, chunk set (t&7)+8i.
    if (threadIdx.x < 512) {
        const int r = threadIdx.x >> 3;          // 0..63
        const int q = threadIdx.x & 7;
        int mm = m0 + r;
        int mv = (mm < M) ? mm : 0;
        if (MODE == 0) {
            if (mm >= M) mv = M - 1;
            const float* rowF = Adense + (size_t)mv * Kd;
#pragma unroll
            for (int i = 0; i < 5; ++i) {
                int c = q + i * 8;              // chunk of 4 halfs, c < 40
                if (c * 4 < S2 * 16) {
                    unsigned short h[4];
#pragma unroll
                    for (int e = 0; e < 4; ++e) {
                        int k = c * 4 + e;
                        h[e] = (k < Kd) ? f2bf(rowF[k]) : (unsigned short)0;
                    }
                    uint2 o;
                    o.x = (unsigned int)h[0] | ((unsigned int)h[1] << 16);
                    o.y = (unsigned int)h[2] | ((unsigned int)h[3] << 16);
                    *(uint2*)&smem[r * STR + c * 4] = o;
                }
            }
        } else if (MODE == 3) {
            // chunks of 8 halfs: c<18 -> f_atoms (144 halfs, zero-padded);
            // c in 18..55 -> amsg chunk cc=c-18 = sum of 6 msg rows.
            const float* rowF = Adense + (size_t)mv * Kd;
            const int* nb = b2a + mv * MAXNB;    // b2a slot carries a2b here
#pragma unroll
            for (int i = 0; i < 7; ++i) {
                int c = q + i * 8;
                if (c < 18) {
                    unsigned short h[8];
#pragma unroll
                    for (int e = 0; e < 8; ++e) {
                        int k = c * 8 + e;
                        h[e] = (k < Kd) ? f2bf(rowF[k]) : (unsigned short)0;
                    }
                    uint4 o;
                    o.x = (unsigned int)h[0] | ((unsigned int)h[1] << 16);
                    o.y = (unsigned int)h[2] | ((unsigned int)h[3] << 16);
                    o.z = (unsigned int)h[4] | ((unsigned int)h[5] << 16);
                    o.w = (unsigned int)h[6] | ((unsigned int)h[7] << 16);
                    *(uint4*)&smem[r * STR + c * 8] = o;
                } else if (c < 56) {
                    int cc = c - 18;
                    float sum[8] = {};
#pragma unroll
                    for (int j = 0; j < MAXNB; ++j) {
                        uint4 v = *(const uint4*)&msg[(size_t)nb[j] * RS + cc * 8];
                        unsigned int ww[4] = {v.x, v.y, v.z, v.w};
#pragma unroll
                        for (int p = 0; p < 4; ++p) {
                            sum[p * 2]     += bf2f((unsigned short)(ww[p] & 0xFFFFu));
                            sum[p * 2 + 1] += bf2f((unsigned short)(ww[p] >> 16));
                        }
                    }
                    uint4 o;
                    unsigned int ow[4];
#pragma unroll
                    for (int p = 0; p < 4; ++p)
                        ow[p] = (unsigned int)f2bf(sum[p * 2]) |
                                ((unsigned int)f2bf(sum[p * 2 + 1]) << 16);
                    o = make_uint4(ow[0], ow[1], ow[2], ow[3]);
                    *(uint4*)&smem[r * STR + 144 + cc * 8] = o;
                }
            }
        } else {
            const unsigned short* rowA;
            const unsigned short* rowM = nullptr;
            if (MODE == 1) {
                rowA = amsg + (size_t)b2a[mv] * RS;
                rowM = msg  + (size_t)b2revb[mv] * RS;
            } else {
                rowA = amsg + (size_t)mv * RS;
            }
#pragma unroll
            for (int i = 0; i < 5; ++i) {
                int c = q + i * 8;              // chunk of 8 halfs, c < 38
                if (c < 38) {
                    uint4 o;
                    if (MODE == 1) {
                        uint4 va = *(const uint4*)(rowA + c * 8);
                        uint4 vm = *(const uint4*)(rowM + c * 8);
                        if (RELUMSG) vm = relu4(vm);
                        o = subpack4(va, vm);
                    } else {
                        o = *(const uint4*)(rowA + c * 8);
                    }
                    *(uint4*)&smem[r * STR + c * 8] = o;
                }
            }
        }
    }
    __syncthreads();

    f32x16 acc_lo, acc_hi;
#pragma unroll
    for (int i = 0; i < 16; ++i) { acc_lo[i] = 0.0f; acc_hi[i] = 0.0f; }

    // A1 fragment pointers per row-half (unused by live MODE 0/1/3 paths
    // except legacy MODE 2).
    const unsigned short* pa1_lo = (MODE != 3 && S1 > 0)
        ? (A1 + ((size_t)(blockIdx.x * 2 + 0) * S1 * 64 + lane) * 8) : nullptr;
    const unsigned short* pa1_hi = (MODE != 3 && S1 > 0)
        ? (A1 + ((size_t)(blockIdx.x * 2 + 1) * S1 * 64 + lane) * 8) : nullptr;
    const unsigned short* pb = Bp + ((size_t)w * SBL * 64 + lane) * 8;

    constexpr int STOT = S1 + S2;

    auto loadA = [&](int s, const unsigned short* pa1x, int half) -> bf16x8 {
        if (MODE != 3 && S1 > 0 && s < S1)
            return *(const bf16x8*)(pa1x + (size_t)s * 512);
        int off = (MODE == 3) ? s * 16 : (s - S1) * 16;
        return *(const bf16x8*)&smem[((half << 5) + mrow) * STR + off + quad * 8];
    };

    bf16x8 b0, b1;
    b0 = *(const bf16x8*)(pb);
    if (STOT > 1) b1 = *(const bf16x8*)(pb + 512);

#pragma unroll
    for (int s = 0; s < STOT; s += 2) {
        bf16x8 a_lo = loadA(s, pa1_lo, 0);
        bf16x8 a_hi = loadA(s, pa1_hi, 1);
        acc_lo = __builtin_amdgcn_mfma_f32_32x32x16_bf16(a_lo, b0, acc_lo, 0, 0, 0);
        acc_hi = __builtin_amdgcn_mfma_f32_32x32x16_bf16(a_hi, b0, acc_hi, 0, 0, 0);
        if (s + 2 < STOT) b0 = *(const bf16x8*)(pb + (size_t)(s + 2) * 512);
        if (s + 1 < STOT) {
            bf16x8 a_lo2 = loadA(s + 1, pa1_lo, 0);
            bf16x8 a_hi2 = loadA(s + 1, pa1_hi, 1);
            acc_lo = __builtin_amdgcn_mfma_f32_32x32x16_bf16(a_lo2, b1, acc_lo, 0, 0, 0);
            acc_hi = __builtin_amdgcn_mfma_f32_32x32x16_bf16(a_hi2, b1, acc_hi, 0, 0, 0);
            if (s + 3 < STOT) b1 = *(const bf16x8*)(pb + (size_t)(s + 3) * 512);
        }
    }

    __syncthreads();   // Ast reads done before Cs overwrites the union

    // C/D: col = w*32 + (lane&31), row = half*32 + (reg&3)+8*(reg>>2)+4*quad.
    {
        int col = w * 32 + mrow;
        if (col < 308) {
#pragma unroll
            for (int r = 0; r < 16; ++r) {
                int row = (r & 3) + 8 * (r >> 2) + 4 * quad;
                smem[row * 308 + col] = f2bf(acc_lo[r]);
            }
#pragma unroll
            for (int r = 0; r < 16; ++r) {
                int row = 32 + (r & 3) + 8 * (r >> 2) + 4 * quad;
                smem[row * 308 + col] = f2bf(acc_hi[r]);
            }
        }
    }
    __syncthreads();

    // Coalesced copy-out with fused epilogue math.
    for (int idx = threadIdx.x; idx < 64 * 76; idx += 640) {
        int row = idx / 76, gcol = idx - row * 76;
        int mm = m0 + row;
        if (mm >= M) continue;
        int c0 = gcol * 4;
        uint2 raw = *(const uint2*)&smem[row * 308 + c0];
        uint2 o;
        if (MODE == 0) {
            o = raw;   // raw pre-activation store (relu applied at consumers)
        } else {
            unsigned short h[4] = {(unsigned short)(raw.x & 0xFFFFu), (unsigned short)(raw.x >> 16),
                                   (unsigned short)(raw.y & 0xFFFFu), (unsigned short)(raw.y >> 16)};
            float v[4];
#pragma unroll
            for (int e = 0; e < 4; ++e) v[e] = bf2f(h[e]);
            if (MODE == 1) {
                uint2 iv = *(const uint2*)&inp_add[(size_t)mm * RS + c0];
                v[0] += bf2f((unsigned short)(iv.x & 0xFFFFu));
                v[1] += bf2f((unsigned short)(iv.x >> 16));
                v[2] += bf2f((unsigned short)(iv.y & 0xFFFFu));
                v[3] += bf2f((unsigned short)(iv.y >> 16));
            } else {
#pragma unroll
                for (int e = 0; e < 4; ++e) v[e] += (c0 + e < H) ? bias[c0 + e] : 0.0f;
            }
#pragma unroll
            for (int e = 0; e < 4; ++e) h[e] = f2bf(fmaxf(v[e], 0.0f));
            o.x = (unsigned int)h[0] | ((unsigned int)h[1] << 16);
            o.y = (unsigned int)h[2] | ((unsigned int)h[3] << 16);
        }
        *(uint2*)&out[(size_t)mm * RS + c0] = o;
    }
}

// ---------------------------------------------------------------------------
__global__ void __launch_bounds__(128)
segmean_kernel(const unsigned short* __restrict__ ah,
               const int* __restrict__ mol_id, int n_atoms,
               float* __restrict__ out)
{
    int m = blockIdx.x;
    int lo = 0, hi = n_atoms;
    while (lo < hi) { int mid = (lo + hi) >> 1; if (mol_id[mid] < m) lo = mid + 1; else hi = mid; }
    int start = lo;
    hi = n_atoms;
    while (lo < hi) { int mid = (lo + hi) >> 1; if (mol_id[mid] < m + 1) lo = mid + 1; else hi = mid; }
    int end = lo;

    int c = threadIdx.x;
    float a0 = 0.f, a1 = 0.f, a2 = 0.f;
    for (int a = start; a < end; ++a) {
        const unsigned short* row = ah + (size_t)a * RS;
        a0 += bf2f(row[c]);
        a1 += bf2f(row[c + 128]);
        if (c < H - 256) a2 += bf2f(row[c + 256]);
    }
    float inv = (end > start) ? 1.0f / (float)(end - start) : 0.0f;
    float* orow = out + (size_t)m * H;
    orow[c] = a0 * inv;
    orow[c + 128] = a1 * inv;
    if (c < H - 256) orow[c + 256] = a2 * inv;
}

// ---------------------------------------------------------------------------
extern "C" void kernel_launch(void* const* d_in, const int* in_sizes, int n_in,
                              void* d_out, int out_size, void* d_ws, size_t ws_size,
                              hipStream_t stream)
{
    const float* f_atoms = (const float*)d_in[0];
    const float* f_bonds = (const float*)d_in[1];
    const int*   a2b     = (const int*)d_in[2];
    const int*   b2a     = (const int*)d_in[3];
    const int*   b2revb  = (const int*)d_in[4];
    const int*   mol_id  = (const int*)d_in[5];
    const float* W_i     = (const float*)d_in[7];
    const float* W_h     = (const float*)d_in[8];
    const float* W_o     = (const float*)d_in[9];
    const float* b_o     = (const float*)d_in[10];

    const int n_atoms   = in_sizes[5];
    const int n_bonds   = in_sizes[3];
    const int atom_fdim = in_sizes[0] / n_atoms;   // 133
    const int bond_fdim = in_sizes[1] / n_bonds;   // 147
    const int n_mols    = out_size / H;            // 2000

    const int gAtoms  = (n_atoms + 63) / 64;       // 64-row blocks
    const int gBonds  = (n_bonds + 63) / 64;

    const size_t bondsRS = (size_t)n_bonds * RS;
    const size_t atomsRS = (size_t)n_atoms * RS;
    const size_t wihSz   = 10 * 30 * 512;
    const size_t woSz    = 10 * 29 * 512;
    const size_t wh19Sz  = 10 * 19 * 512;

    // Layout (halfs): inp | msgB | amsg | wih | wo | wh19 | ah
    // Overlays: iter-2 mp writes message2 in-place over inp (audited safe).
    unsigned short* inp  = (unsigned short*)d_ws;
    unsigned short* msgB = inp  + bondsRS;
    unsigned short* amsg = msgB + bondsRS;
    unsigned short* wih  = amsg + atomsRS;
    unsigned short* wo   = wih  + wihSz;
    unsigned short* wh19 = wo   + woSz;
    unsigned short* ah   = wh19 + wh19Sz;

    dim3 blk(256);
    dim3 gblk(640);
    const int aggBlocks = (n_atoms * 38 + 255) / 256;

    pack_b<<<(10 * 30 * 64 + 255) / 256, blk, 0, stream>>>(W_i, W_h, wih, bond_fdim, 10, H, 30);
    pack_b<<<(10 * 19 * 64 + 255) / 256, blk, 0, stream>>>(W_h, W_h, wh19, H, 19, 0, 19);
    pack_b<<<(10 * 29 * 64 + 255) / 256, blk, 0, stream>>>(W_o, W_o + (size_t)atom_fdim * H, wo,
                                                           atom_fdim, 9, H, 29);

    // init: inp = f_bonds @ W_i  (raw; f_bonds staged fp32->bf16 in-kernel)
    gemm_fused<0, 10, 30, 0, 0><<<gBonds, gblk, 0, stream>>>(
        nullptr, nullptr, nullptr, nullptr, nullptr, wih, nullptr, nullptr,
        f_bonds, bond_fdim, inp, n_bonds);

    // iter 1: message1 = relu(inp + (amsg[b2a] - relu(inp[b2revb])) @ W_h) -> msgB
    aggregate_row<1><<<aggBlocks, blk, 0, stream>>>(inp, a2b, amsg, n_atoms);
    gemm_fused<0, 19, 19, 1, 1><<<gBonds, gblk, 0, stream>>>(
        nullptr, amsg, inp, b2a, b2revb, wh19, nullptr, inp, nullptr, 0, msgB, n_bonds);

    // iter 2: message2 -> inp (in-place; inp only read by this kernel's epilogue)
    aggregate_row<0><<<aggBlocks, blk, 0, stream>>>(msgB, a2b, amsg, n_atoms);
    gemm_fused<0, 19, 19, 1, 0><<<gBonds, gblk, 0, stream>>>(
        nullptr, amsg, msgB, b2a, b2revb, wh19, nullptr, inp, nullptr, 0, inp, n_bonds);

    // cat GEMM (fused final aggregate + f_atoms pack):
    // ah = relu([f_atoms | Sum_j msg2[a2b]] @ W_o + b_o)
    gemm_fused<9, 19, 29, 3, 0><<<gAtoms, gblk, 0, stream>>>(
        nullptr, nullptr, inp, a2b, nullptr, wo, b_o, nullptr,
        f_atoms, atom_fdim, ah, n_atoms);

    segmean_kernel<<<n_mols, dim3(128), 0, stream>>>(ah, mol_id, n_atoms, (float*)d_out);
}

// Round 10
// 473.644 us; speedup vs baseline: 1.0990x; 1.0032x over previous
//
#include <hip/hip_runtime.h>
#include <cstddef>

#define H 300
#define RS 304            // row stride (halfs) for row-major bf16 buffers
#define MAXNB 6
#define ASTR 312          // LDS A-tile stride (halfs); 624 B rows, 16B-divisible

typedef __attribute__((ext_vector_type(8)))  short bf16x8;
typedef __attribute__((ext_vector_type(16))) float f32x16;

__device__ __forceinline__ float bf2f(unsigned short u) {
    return __uint_as_float(((unsigned int)u) << 16);
}
__device__ __forceinline__ unsigned short f2bf(float f) {
    unsigned int u = __float_as_uint(f);
    u += 0x7FFFu + ((u >> 16) & 1u);
    return (unsigned short)(u >> 16);
}
__device__ __forceinline__ unsigned int sub2bf(unsigned int a, unsigned int b) {
    float d0 = bf2f((unsigned short)(a & 0xFFFFu)) - bf2f((unsigned short)(b & 0xFFFFu));
    float d1 = bf2f((unsigned short)(a >> 16))     - bf2f((unsigned short)(b >> 16));
    return (unsigned int)f2bf(d0) | ((unsigned int)f2bf(d1) << 16);
}
// relu on two packed bf16 (zero the negative halves) — bit-exact vs fp32 relu.
__device__ __forceinline__ unsigned int relu2(unsigned int w) {
    unsigned int r = w;
    if (w & 0x80000000u) r &= 0x0000FFFFu;
    if (w & 0x00008000u) r &= 0xFFFF0000u;
    return r;
}
__device__ __forceinline__ uint4 relu4(uint4 v) {
    v.x = relu2(v.x); v.y = relu2(v.y); v.z = relu2(v.z); v.w = relu2(v.w);
    return v;
}
__device__ __forceinline__ uint4 subpack4(uint4 a, uint4 b) {
    uint4 r;
    r.x = sub2bf(a.x, b.x); r.y = sub2bf(a.y, b.y);
    r.z = sub2bf(a.z, b.z); r.w = sub2bf(a.w, b.w);
    return r;
}

// ---------------------------------------------------------------------------
// Fragment layout: element (m,k) at buf[((m_blk*S + s)*64 + lane)*8 + j],
// m = m_blk*32 + (lane&31), k = s*16 + (lane>>5)*8 + j. Same for B with n.

// Coalesced fragment pack for dense fp32 (f_atoms): one block per 64-row tile;
// stage rows coalesced into LDS (bf16), then write fragments 16B/lane.
template<int S>
__global__ void __launch_bounds__(256)
pack_a_f32_c(const float* __restrict__ src, unsigned short* __restrict__ dst,
             int M, int K)
{
    __shared__ unsigned short sm[64 * 152];
    const int m0 = blockIdx.x * 64;
    const int r = threadIdx.x >> 2;
    const int q = threadIdx.x & 3;
    int mv = m0 + r; if (mv >= M) mv = M - 1;
    const float* rowF = src + (size_t)mv * K;
#pragma unroll
    for (int i = 0; i < (S * 4 + 3) / 4; ++i) {
        int c = q + i * 4;                    // chunk of 4 halfs
        if (c * 4 < S * 16) {
            unsigned short h[4];
#pragma unroll
            for (int e = 0; e < 4; ++e) {
                int k = c * 4 + e;
                h[e] = (k < K) ? f2bf(rowF[k]) : (unsigned short)0;
            }
            uint2 o;
            o.x = (unsigned int)h[0] | ((unsigned int)h[1] << 16);
            o.y = (unsigned int)h[2] | ((unsigned int)h[3] << 16);
            *(uint2*)&sm[r * 152 + c * 4] = o;
        }
    }
    __syncthreads();
    for (int j = threadIdx.x; j < 2 * S * 64; j += 256) {
        int lane = j & 63;
        int t = j >> 6;
        int s = t % S;
        int mb2 = t / S;
        uint4 v = *(const uint4*)&sm[(mb2 * 32 + (lane & 31)) * 152 + s * 16 + (lane >> 5) * 8];
        int m_blk = blockIdx.x * 2 + mb2;
        *(uint4*)&dst[((size_t)(m_blk * S + s) * 64 + lane) * 8] = v;
    }
}

// ---------------------------------------------------------------------------
__device__ __forceinline__ void
pack_b_body(int g, const float* __restrict__ src1, const float* __restrict__ src2,
            unsigned short* __restrict__ dst, int K1, int S1, int K2, int SB)
{
    if (g >= 10 * SB * 64) return;
    int lane = g & 63;
    int t = g >> 6;
    int s = t % SB;
    int n_blk = t / SB;
    int n = n_blk * 32 + (lane & 31);
    unsigned int w[4];
#pragma unroll
    for (int p = 0; p < 4; ++p) {
        unsigned short h[2];
#pragma unroll
        for (int e = 0; e < 2; ++e) {
            int kf = s * 16 + (lane >> 5) * 8 + p * 2 + e;
            float v = 0.0f;
            if (n < H) {
                if (s < S1) {
                    if (kf < K1) v = src1[(size_t)kf * H + n];
                } else {
                    int k2 = kf - S1 * 16;
                    if (k2 < K2) v = src2[(size_t)k2 * H + n];
                }
            }
            h[e] = f2bf(v);
        }
        w[p] = (unsigned int)h[0] | ((unsigned int)h[1] << 16);
    }
    *(uint4*)&dst[(size_t)g * 8] = make_uint4(w[0], w[1], w[2], w[3]);
}

// All three B packs in one dispatch (block-range switch) — R10: removes 2
// launch gaps vs 3 separate pack_b dispatches.
__global__ void __launch_bounds__(256)
pack_b_all(const float* __restrict__ Wi, const float* __restrict__ Wh,
           const float* __restrict__ Wo,
           unsigned short* __restrict__ wih, unsigned short* __restrict__ wh19,
           unsigned short* __restrict__ wo, int bond_fdim, int atom_fdim)
{
    const int B0 = (10 * 30 * 64 + 255) / 256;   // 75
    const int B1 = (10 * 19 * 64 + 255) / 256;   // 48
    int b = blockIdx.x;
    if (b < B0) {
        pack_b_body(b * 256 + threadIdx.x, Wi, Wh, wih, bond_fdim, 10, H, 30);
    } else if (b < B0 + B1) {
        pack_b_body((b - B0) * 256 + threadIdx.x, Wh, Wh, wh19, H, 19, 0, 19);
    } else {
        pack_b_body((b - B0 - B1) * 256 + threadIdx.x, Wo,
                    Wo + (size_t)atom_fdim * H, wo, atom_fdim, 9, H, 29);
    }
}

// ---------------------------------------------------------------------------
// amsg[a][:] = sum_j maybe_relu(msg[a2b[a][j]][:]). One thread per 8 halfs.
template<int RELU>
__global__ void __launch_bounds__(256)
aggregate_row(const unsigned short* __restrict__ msg, const int* __restrict__ a2b,
              unsigned short* __restrict__ amsg, int n_atoms)
{
    int gid = blockIdx.x * 256 + threadIdx.x;
    int total = n_atoms * 38;
    if (gid >= total) return;
    int atom = gid / 38;
    int g8 = gid - atom * 38;
    const int* nb = a2b + atom * MAXNB;
    float sum[8] = {};
#pragma unroll
    for (int j = 0; j < MAXNB; ++j) {
        int b = nb[j];
        uint4 v = *(const uint4*)&msg[(size_t)b * RS + g8 * 8];
        if (RELU) v = relu4(v);
        unsigned int ww[4] = {v.x, v.y, v.z, v.w};
#pragma unroll
        for (int p = 0; p < 4; ++p) {
            sum[p * 2]     += bf2f((unsigned short)(ww[p] & 0xFFFFu));
            sum[p * 2 + 1] += bf2f((unsigned short)(ww[p] >> 16));
        }
    }
    unsigned int ow[4];
#pragma unroll
    for (int p = 0; p < 4; ++p)
        ow[p] = (unsigned int)f2bf(sum[p * 2]) | ((unsigned int)f2bf(sum[p * 2 + 1]) << 16);
    *(uint4*)&amsg[(size_t)atom * RS + g8 * 8] = make_uint4(ow[0], ow[1], ow[2], ow[3]);
}

// ---------------------------------------------------------------------------
// Fused MFMA GEMM. Geometry = R3/R7 (best): 64-row tile, 640 thr / 10 waves,
// wave = 1 N-block x 2 row-halves, acc[2] = 32 AGPR, launch_bounds(640,8),
// LDS epilogue.
// R10: MODE 3 keeps R9's fused final-aggregate staging (6-gather sum, no
// aggregate_row dispatch, no amsg round-trip) but the f_atoms K-steps come
// from packed A1 fragments again (S1=9, 16B in-loop global frag loads) ->
// LDS back to 39.9KB (R9's 58.4KB all-LDS tile dropped cat to 2 blocks/CU,
// occupancy 22%, 101us).
// MODE 0 (init): A = dense fp32 Adense staged fp32->bf16 in LDS. out = raw A@B.
// MODE 1 (mp):   A = LDS-staged (amsg[b2a[m]] - maybe_relu(msg[b2revb[m]])).
//                out = relu(A@B + inp_add).
// MODE 3 (catf): A = [A1 frags | LDS-staged Sum_j msg[a2b]]. out = relu(A@B+bias).
template<int S1, int S2, int SBL, int MODE, int RELUMSG>
__global__ void __launch_bounds__(640, 8)
gemm_fused(const unsigned short* __restrict__ A1,
           const unsigned short* __restrict__ amsg,
           const unsigned short* __restrict__ msg,
           const int* __restrict__ b2a, const int* __restrict__ b2revb,
           const unsigned short* __restrict__ Bp,
           const float* __restrict__ bias,
           const unsigned short* __restrict__ inp_add,
           const float* __restrict__ Adense, int Kd,
           unsigned short* __restrict__ out, int M)
{
    __shared__ __align__(16) unsigned short smem[64 * ASTR]; // Ast / Cs union

    const int lane  = threadIdx.x & 63;
    const int w     = threadIdx.x >> 6;          // 0..9: N-block index
    const int mrow  = lane & 31;
    const int quad  = lane >> 5;
    const int m0    = blockIdx.x * 64;

    // ---- Stage A-tile: 512 threads, 8 threads/row, chunk set (t&7)+8i.
    if (threadIdx.x < 512) {
        const int r = threadIdx.x >> 3;          // 0..63
        const int q = threadIdx.x & 7;
        int mm = m0 + r;
        int mv = (mm < M) ? mm : 0;
        if (MODE == 0) {
            if (mm >= M) mv = M - 1;
            const float* rowF = Adense + (size_t)mv * Kd;
#pragma unroll
            for (int i = 0; i < 5; ++i) {
                int c = q + i * 8;              // chunk of 4 halfs, c < 40
                if (c * 4 < S2 * 16) {
                    unsigned short h[4];
#pragma unroll
                    for (int e = 0; e < 4; ++e) {
                        int k = c * 4 + e;
                        h[e] = (k < Kd) ? f2bf(rowF[k]) : (unsigned short)0;
                    }
                    uint2 o;
                    o.x = (unsigned int)h[0] | ((unsigned int)h[1] << 16);
                    o.y = (unsigned int)h[2] | ((unsigned int)h[3] << 16);
                    *(uint2*)&smem[r * ASTR + c * 4] = o;
                }
            }
        } else if (MODE == 3) {
            // Fused final aggregate: chunk c (8 halfs) = sum of 6 msg rows.
            const int* nb = b2a + mv * MAXNB;    // b2a slot carries a2b here
#pragma unroll
            for (int i = 0; i < 5; ++i) {
                int c = q + i * 8;
                if (c < 38) {
                    float sum[8] = {};
#pragma unroll
                    for (int j = 0; j < MAXNB; ++j) {
                        uint4 v = *(const uint4*)&msg[(size_t)nb[j] * RS + c * 8];
                        unsigned int ww[4] = {v.x, v.y, v.z, v.w};
#pragma unroll
                        for (int p = 0; p < 4; ++p) {
                            sum[p * 2]     += bf2f((unsigned short)(ww[p] & 0xFFFFu));
                            sum[p * 2 + 1] += bf2f((unsigned short)(ww[p] >> 16));
                        }
                    }
                    unsigned int ow[4];
#pragma unroll
                    for (int p = 0; p < 4; ++p)
                        ow[p] = (unsigned int)f2bf(sum[p * 2]) |
                                ((unsigned int)f2bf(sum[p * 2 + 1]) << 16);
                    *(uint4*)&smem[r * ASTR + c * 8] = make_uint4(ow[0], ow[1], ow[2], ow[3]);
                }
            }
        } else {
            const unsigned short* rowA;
            const unsigned short* rowM = nullptr;
            if (MODE == 1) {
                rowA = amsg + (size_t)b2a[mv] * RS;
                rowM = msg  + (size_t)b2revb[mv] * RS;
            } else {
                rowA = amsg + (size_t)mv * RS;
            }
#pragma unroll
            for (int i = 0; i < 5; ++i) {
                int c = q + i * 8;              // chunk of 8 halfs, c < 38
                if (c < 38) {
                    uint4 o;
                    if (MODE == 1) {
                        uint4 va = *(const uint4*)(rowA + c * 8);
                        uint4 vm = *(const uint4*)(rowM + c * 8);
                        if (RELUMSG) vm = relu4(vm);
                        o = subpack4(va, vm);
                    } else {
                        o = *(const uint4*)(rowA + c * 8);
                    }
                    *(uint4*)&smem[r * ASTR + c * 8] = o;
                }
            }
        }
    }
    __syncthreads();

    f32x16 acc_lo, acc_hi;
#pragma unroll
    for (int i = 0; i < 16; ++i) { acc_lo[i] = 0.0f; acc_hi[i] = 0.0f; }

    // A1 fragment pointers per row-half (32-row m_blk granularity).
    const unsigned short* pa1_lo = (S1 > 0)
        ? (A1 + ((size_t)(blockIdx.x * 2 + 0) * S1 * 64 + lane) * 8) : nullptr;
    const unsigned short* pa1_hi = (S1 > 0)
        ? (A1 + ((size_t)(blockIdx.x * 2 + 1) * S1 * 64 + lane) * 8) : nullptr;
    const unsigned short* pb = Bp + ((size_t)w * SBL * 64 + lane) * 8;

    constexpr int STOT = S1 + S2;

    auto loadA = [&](int s, const unsigned short* pa1x, int half) -> bf16x8 {
        if (S1 > 0 && s < S1) return *(const bf16x8*)(pa1x + (size_t)s * 512);
        return *(const bf16x8*)&smem[((half << 5) + mrow) * ASTR + (s - S1) * 16 + quad * 8];
    };

    bf16x8 b0, b1;
    b0 = *(const bf16x8*)(pb);
    if (STOT > 1) b1 = *(const bf16x8*)(pb + 512);

#pragma unroll
    for (int s = 0; s < STOT; s += 2) {
        bf16x8 a_lo = loadA(s, pa1_lo, 0);
        bf16x8 a_hi = loadA(s, pa1_hi, 1);
        acc_lo = __builtin_amdgcn_mfma_f32_32x32x16_bf16(a_lo, b0, acc_lo, 0, 0, 0);
        acc_hi = __builtin_amdgcn_mfma_f32_32x32x16_bf16(a_hi, b0, acc_hi, 0, 0, 0);
        if (s + 2 < STOT) b0 = *(const bf16x8*)(pb + (size_t)(s + 2) * 512);
        if (s + 1 < STOT) {
            bf16x8 a_lo2 = loadA(s + 1, pa1_lo, 0);
            bf16x8 a_hi2 = loadA(s + 1, pa1_hi, 1);
            acc_lo = __builtin_amdgcn_mfma_f32_32x32x16_bf16(a_lo2, b1, acc_lo, 0, 0, 0);
            acc_hi = __builtin_amdgcn_mfma_f32_32x32x16_bf16(a_hi2, b1, acc_hi, 0, 0, 0);
            if (s + 3 < STOT) b1 = *(const bf16x8*)(pb + (size_t)(s + 3) * 512);
        }
    }

    __syncthreads();   // Ast reads done before Cs overwrites the union

    // C/D: col = w*32 + (lane&31), row = half*32 + (reg&3)+8*(reg>>2)+4*quad.
    {
        int col = w * 32 + mrow;
        if (col < 308) {
#pragma unroll
            for (int r = 0; r < 16; ++r) {
                int row = (r & 3) + 8 * (r >> 2) + 4 * quad;
                smem[row * 308 + col] = f2bf(acc_lo[r]);
            }
#pragma unroll
            for (int r = 0; r < 16; ++r) {
                int row = 32 + (r & 3) + 8 * (r >> 2) + 4 * quad;
                smem[row * 308 + col] = f2bf(acc_hi[r]);
            }
        }
    }
    __syncthreads();

    // Coalesced copy-out with fused epilogue math.
    for (int idx = threadIdx.x; idx < 64 * 76; idx += 640) {
        int row = idx / 76, gcol = idx - row * 76;
        int mm = m0 + row;
        if (mm >= M) continue;
        int c0 = gcol * 4;
        uint2 raw = *(const uint2*)&smem[row * 308 + c0];
        uint2 o;
        if (MODE == 0) {
            o = raw;   // raw pre-activation store (relu applied at consumers)
        } else {
            unsigned short h[4] = {(unsigned short)(raw.x & 0xFFFFu), (unsigned short)(raw.x >> 16),
                                   (unsigned short)(raw.y & 0xFFFFu), (unsigned short)(raw.y >> 16)};
            float v[4];
#pragma unroll
            for (int e = 0; e < 4; ++e) v[e] = bf2f(h[e]);
            if (MODE == 1) {
                uint2 iv = *(const uint2*)&inp_add[(size_t)mm * RS + c0];
                v[0] += bf2f((unsigned short)(iv.x & 0xFFFFu));
                v[1] += bf2f((unsigned short)(iv.x >> 16));
                v[2] += bf2f((unsigned short)(iv.y & 0xFFFFu));
                v[3] += bf2f((unsigned short)(iv.y >> 16));
            } else {
#pragma unroll
                for (int e = 0; e < 4; ++e) v[e] += (c0 + e < H) ? bias[c0 + e] : 0.0f;
            }
#pragma unroll
            for (int e = 0; e < 4; ++e) h[e] = f2bf(fmaxf(v[e], 0.0f));
            o.x = (unsigned int)h[0] | ((unsigned int)h[1] << 16);
            o.y = (unsigned int)h[2] | ((unsigned int)h[3] << 16);
        }
        *(uint2*)&out[(size_t)mm * RS + c0] = o;
    }
}

// ---------------------------------------------------------------------------
__global__ void __launch_bounds__(128)
segmean_kernel(const unsigned short* __restrict__ ah,
               const int* __restrict__ mol_id, int n_atoms,
               float* __restrict__ out)
{
    int m = blockIdx.x;
    int lo = 0, hi = n_atoms;
    while (lo < hi) { int mid = (lo + hi) >> 1; if (mol_id[mid] < m) lo = mid + 1; else hi = mid; }
    int start = lo;
    hi = n_atoms;
    while (lo < hi) { int mid = (lo + hi) >> 1; if (mol_id[mid] < m + 1) lo = mid + 1; else hi = mid; }
    int end = lo;

    int c = threadIdx.x;
    float a0 = 0.f, a1 = 0.f, a2 = 0.f;
    for (int a = start; a < end; ++a) {
        const unsigned short* row = ah + (size_t)a * RS;
        a0 += bf2f(row[c]);
        a1 += bf2f(row[c + 128]);
        if (c < H - 256) a2 += bf2f(row[c + 256]);
    }
    float inv = (end > start) ? 1.0f / (float)(end - start) : 0.0f;
    float* orow = out + (size_t)m * H;
    orow[c] = a0 * inv;
    orow[c + 128] = a1 * inv;
    if (c < H - 256) orow[c + 256] = a2 * inv;
}

// ---------------------------------------------------------------------------
extern "C" void kernel_launch(void* const* d_in, const int* in_sizes, int n_in,
                              void* d_out, int out_size, void* d_ws, size_t ws_size,
                              hipStream_t stream)
{
    const float* f_atoms = (const float*)d_in[0];
    const float* f_bonds = (const float*)d_in[1];
    const int*   a2b     = (const int*)d_in[2];
    const int*   b2a     = (const int*)d_in[3];
    const int*   b2revb  = (const int*)d_in[4];
    const int*   mol_id  = (const int*)d_in[5];
    const float* W_i     = (const float*)d_in[7];
    const float* W_h     = (const float*)d_in[8];
    const float* W_o     = (const float*)d_in[9];
    const float* b_o     = (const float*)d_in[10];

    const int n_atoms   = in_sizes[5];
    const int n_bonds   = in_sizes[3];
    const int atom_fdim = in_sizes[0] / n_atoms;   // 133
    const int bond_fdim = in_sizes[1] / n_bonds;   // 147
    const int n_mols    = out_size / H;            // 2000

    const int gAtoms  = (n_atoms + 63) / 64;       // 64-row blocks
    const int gBonds  = (n_bonds + 63) / 64;

    const size_t bondsRS = (size_t)n_bonds * RS;
    const size_t atomsRS = (size_t)n_atoms * RS;
    const size_t wihSz   = 10 * 30 * 512;
    const size_t woSz    = 10 * 29 * 512;
    const size_t wh19Sz  = 10 * 19 * 512;

    // Layout (halfs): inp | msgB | amsg | wih | wo | wh19 | ah
    // Overlays: iter-2 mp writes message2 in-place over inp (audited safe);
    //           fap (14.4 MB) overlays msgB (dead after mp2; inp stays live
    //           because the fused cat reads it).
    unsigned short* inp  = (unsigned short*)d_ws;
    unsigned short* msgB = inp  + bondsRS;
    unsigned short* amsg = msgB + bondsRS;
    unsigned short* wih  = amsg + atomsRS;
    unsigned short* wo   = wih  + wihSz;
    unsigned short* wh19 = wo   + woSz;
    unsigned short* ah   = wh19 + wh19Sz;
    unsigned short* fap  = msgB;

    dim3 blk(256);
    dim3 gblk(640);
    const int aggBlocks = (n_atoms * 38 + 255) / 256;
    const int packBlocks = (10 * 30 * 64 + 255) / 256 + (10 * 19 * 64 + 255) / 256
                         + (10 * 29 * 64 + 255) / 256;   // 75 + 48 + 73 = 196

    // All B packs in one dispatch.
    pack_b_all<<<packBlocks, blk, 0, stream>>>(W_i, W_h, W_o, wih, wh19, wo,
                                               bond_fdim, atom_fdim);

    // init: inp = f_bonds @ W_i  (raw; f_bonds staged fp32->bf16 in-kernel)
    gemm_fused<0, 10, 30, 0, 0><<<gBonds, gblk, 0, stream>>>(
        nullptr, nullptr, nullptr, nullptr, nullptr, wih, nullptr, nullptr,
        f_bonds, bond_fdim, inp, n_bonds);

    // iter 1: message1 = relu(inp + (amsg[b2a] - relu(inp[b2revb])) @ W_h) -> msgB
    aggregate_row<1><<<aggBlocks, blk, 0, stream>>>(inp, a2b, amsg, n_atoms);
    gemm_fused<0, 19, 19, 1, 1><<<gBonds, gblk, 0, stream>>>(
        nullptr, amsg, inp, b2a, b2revb, wh19, nullptr, inp, nullptr, 0, msgB, n_bonds);

    // iter 2: message2 -> inp (in-place; inp only read by this kernel's epilogue)
    aggregate_row<0><<<aggBlocks, blk, 0, stream>>>(msgB, a2b, amsg, n_atoms);
    gemm_fused<0, 19, 19, 1, 0><<<gBonds, gblk, 0, stream>>>(
        nullptr, amsg, msgB, b2a, b2revb, wh19, nullptr, inp, nullptr, 0, inp, n_bonds);

    // f_atoms pack (msgB dead after mp2 -> fap overlays it)
    pack_a_f32_c<9><<<gAtoms, blk, 0, stream>>>(f_atoms, fap, n_atoms, atom_fdim);

    // cat GEMM (fused final aggregate; f_atoms via packed A1 fragments):
    // ah = relu([f_atoms | Sum_j msg2[a2b]] @ W_o + b_o)
    gemm_fused<9, 19, 29, 3, 0><<<gAtoms, gblk, 0, stream>>>(
        fap, nullptr, inp, a2b, nullptr, wo, b_o, nullptr,
        nullptr, 0, ah, n_atoms);

    segmean_kernel<<<n_mols, dim3(128), 0, stream>>>(ah, mol_id, n_atoms, (float*)d_out);
}